// Round 4
// baseline (297.039 us; speedup 1.0000x reference)
//
#include <hip/hip_runtime.h>
#include <math.h>

#define NA 10000
#define NE 40000

typedef float f4 __attribute__((ext_vector_type(4)));
typedef float f16v __attribute__((ext_vector_type(16)));
typedef __bf16 bf16x8 __attribute__((ext_vector_type(8)));

union U8 { unsigned short us[8]; bf16x8 v; };

__device__ __forceinline__ unsigned short bf_rne(float x){
  unsigned u = __float_as_uint(x);
  unsigned r = (u + 0x7fffu + ((u>>16)&1u)) >> 16;
  return (unsigned short)r;
}
__device__ __forceinline__ float bf_to_f(unsigned short h){
  return __uint_as_float(((unsigned)h)<<16);
}

// ---------------- fold BN into weights; build MFMA fragment tables; histogram ----------------
// Bh/Bl: enc GEMM B-operands for 32x32x16: [d(64)][ft(2)][lane(64)][j(8)] bf16.
//   k=(lane>>5)*8+j, n = d*64 + ft*32 + (lane&31)
//   k<12 -> Wfold[n][k] hi/lo; k==12 -> bias_fold[n] hi/lo; k>12 -> 0
__global__ void k_pre(const float* __restrict__ encW, const float* __restrict__ encB,
                      const float* __restrict__ eg, const float* __restrict__ ebt,
                      const float* __restrict__ em, const float* __restrict__ ev,
                      const float* __restrict__ attW, const float* __restrict__ attB,
                      const float* __restrict__ agm, const float* __restrict__ abt,
                      const float* __restrict__ amn, const float* __restrict__ avr,
                      const float* __restrict__ wih, const float* __restrict__ whh,
                      const int* __restrict__ bidx,
                      unsigned short* __restrict__ Bh, unsigned short* __restrict__ Bl,
                      float* __restrict__ attWt, float* __restrict__ attBf,
                      float* __restrict__ wq, int* __restrict__ cnt)
{
  int i0 = blockIdx.x*blockDim.x + threadIdx.x;
  int stride = gridDim.x*blockDim.x;
  for (int i=i0; i<65536; i+=stride){
    int j = i&7, l = (i>>3)&63, t = i>>9;
    int d = t>>1, ft = t&1;
    int k = ((l>>5)<<3)+j;
    int n = d*64 + ft*32 + (l&31);
    float s = eg[n]*rsqrtf(ev[n]+1e-6f);
    unsigned short vh=0, vl=0;
    if (k<12){
      float w = encW[n*12+k]*s;
      unsigned short hi = bf_rne(w);
      vh = hi; vl = bf_rne(w - bf_to_f(hi));
    } else if (k==12){
      float b = (encB[n]-em[n])*s + ebt[n];
      unsigned short hi = bf_rne(b);
      vh = hi; vl = bf_rne(b - bf_to_f(hi));
    }
    Bh[i] = vh; Bl[i] = vl;
  }
  for (int i=i0; i<4096; i+=stride){
    int k = i>>6, f = i&63;
    float s = agm[f]*rsqrtf(avr[f]+1e-6f);
    attWt[i] = attW[f*64+k]*s;
  }
  for (int f=i0; f<64; f+=stride){
    float s = agm[f]*rsqrtf(avr[f]+1e-6f);
    attBf[f] = (attB[f]-amn[f])*s + abt[f];
  }
  for (int i=i0; i<24576; i+=stride){
    int j=i&3, f=(i>>2)&63, idx2=i>>8;
    int g=idx2>>4, kg=idx2&15, k=kg*4+j;
    wq[i] = (g<3)? wih[(g*64+f)*64+k] : whh[((g-3)*64+f)*64+k];
  }
  for (int e=i0; e<NE; e+=stride) atomicAdd(&cnt[bidx[e*2]], 1);
}

// ---------------- exclusive scan over degree ----------------
__global__ __launch_bounds__(256) void k_scan(const int* __restrict__ cnt,
                                              int* __restrict__ rowstart,
                                              int* __restrict__ wofs){
  __shared__ int sPart[256];
  int t = threadIdx.x;
  int lo = t*40;
  int hi = lo+40; if (hi > NA) hi = NA; if (lo > NA) lo = NA;
  int sum = 0;
  for (int i=lo;i<hi;i++) sum += cnt[i];
  sPart[t] = sum;
  __syncthreads();
  for (int off=1; off<256; off<<=1){
    int v = 0;
    if (t >= off) v = sPart[t-off];
    __syncthreads();
    if (t >= off) sPart[t] += v;
    __syncthreads();
  }
  int run = sPart[t] - sum;
  for (int i=lo;i<hi;i++){
    rowstart[i] = run; wofs[i] = run;
    run += cnt[i];
  }
  if (t==255) rowstart[NA] = run;
}

__global__ void k_scatter(const int* __restrict__ bidx, int* __restrict__ wofs,
                          int* __restrict__ elist){
  int e = blockIdx.x*blockDim.x + threadIdx.x;
  if (e < NE){
    int tg = bidx[e*2];
    int pos = atomicAdd(&wofs[tg], 1);
    elist[pos] = e;
  }
}

// ---------------- fused: enc GEMM + contraction + score + softmax + context + ELU ----------------
// Block b owns atoms {a : rowstart[a] in [64b, 64b+64)}; edges CSR-contiguous, <=128.
// 4 waves; wave w = 32-edge M-tile, full 64-d sweep, 32x32x16 bf16 MFMA x3 (hi/lo split).
__global__ __launch_bounds__(256) void k_edge(
  const float* __restrict__ atom, const int* __restrict__ bidx, const float* __restrict__ bond,
  const unsigned short* __restrict__ Bhg, const unsigned short* __restrict__ Blg,
  const float* __restrict__ alW, const float* __restrict__ alB,
  const float* __restrict__ attWt, const float* __restrict__ attBf,
  const int* __restrict__ rowstart, const int* __restrict__ elist,
  float* __restrict__ cfout)
{
  __shared__ float sA[8448];       // atomT [d(64)][stride 132]; later reused as attW (4096)
  __shared__ float sNb[128*65];    // neighbor tile [le][f]
  __shared__ int   sEl[128];
  __shared__ int   sNbr[128];
  __shared__ float sScore[128];
  __shared__ float sBias[64];
  __shared__ int   sMeta[4];

  int tid = threadIdx.x;
  int l = tid & 63;
  int w = tid >> 6;
  int g = l >> 5;
  int em = l & 31;
  int b = blockIdx.x;

  if (tid == 0){
    int T1 = b*64, T2 = T1+64;
    int lo=0, hi=NA;
    while (lo<hi){ int mid=(lo+hi)>>1; if (rowstart[mid] < T1) lo=mid+1; else hi=mid; }
    int aLo = lo;
    int aHi;
    if (b == 624) aHi = NA;
    else {
      lo=aLo; hi=NA;
      while (lo<hi){ int mid=(lo+hi)>>1; if (rowstart[mid] < T2) lo=mid+1; else hi=mid; }
      aHi = lo;
    }
    sMeta[0]=aLo; sMeta[1]=aHi;
    sMeta[2]=rowstart[aLo]; sMeta[3]=rowstart[aHi];
  }
  __syncthreads();
  int aLo=sMeta[0], aHi=sMeta[1], E0=sMeta[2];
  int nE = sMeta[3]-E0; if (nE>128) nE=128;
  int pad = (nE+31)&~31; if (pad>128) pad=128;

  for (int i=tid; i<nE; i+=256){
    int e = elist[E0+i];
    sEl[i]=e;
    sNbr[i]=bidx[e*2+1];
  }
  __syncthreads();
  // stage atomT (coalesced global reads): sA[d*132 + le]
  for (int i=tid; i<(nE<<6); i+=256){
    int le=i>>6, d=i&63;
    sA[d*132+le] = atom[(size_t)sNbr[le]*64 + d];
  }
  // zero-fill slack rows up to tile boundary (avoid NaN garbage in contraction)
  for (int i=tid; i<((pad-nE)<<6); i+=256){
    int le=nE+(i>>6), d=i&63;
    sA[d*132+le] = 0.f;
  }

  // A fragments for this wave's tile (edge le = 32w+em), hi/lo split, bias slot k=12
  U8 A1, A2;
  {
    int le_m = (w<<5) + em;
    if (le_m < nE){
      const f4* bp = (const f4*)(bond + (size_t)sEl[le_m]*12);
      f4 b0=bp[0], b1v=bp[1], b2v=bp[2];
      float bv[12] = {b0.x,b0.y,b0.z,b0.w,b1v.x,b1v.y,b1v.z,b1v.w,b2v.x,b2v.y,b2v.z,b2v.w};
      unsigned short hi[12], lo2[12];
      #pragma unroll
      for (int j=0;j<12;j++){ hi[j]=bf_rne(bv[j]); lo2[j]=bf_rne(bv[j]-bf_to_f(hi[j])); }
      #pragma unroll
      for (int j=0;j<8;j++){
        int k = g*8+j;
        A1.us[j] = (k<12)? hi[k] : (k==12? (unsigned short)0x3F80 : (unsigned short)0);
        A2.us[j] = (k<12)? lo2[k] : (unsigned short)0;
      }
    } else {
      #pragma unroll
      for (int j=0;j<8;j++){ A1.us[j]=0; A2.us[j]=0; }
    }
  }
  __syncthreads();

  // MFMA + contraction: full 64-d sweep for this wave's 32-edge tile
  if ((w<<5) < nE){
    f4 nacc[2][4];
    #pragma unroll
    for (int ft=0; ft<2; ft++)
      #pragma unroll
      for (int q=0;q<4;q++) nacc[ft][q] = (f4){0.f,0.f,0.f,0.f};
    f16v cz;
    #pragma unroll
    for (int r=0;r<16;r++) cz[r] = 0.f;

    for (int d=0; d<64; d++){
      f4 ldA[4];
      #pragma unroll
      for (int q=0;q<4;q++) ldA[q] = *(const f4*)&sA[d*132 + (w<<5) + (q<<3) + (g<<2)];
      #pragma unroll
      for (int ft=0; ft<2; ft++){
        U8 bbh, bbl;
        bbh.v = *(const bf16x8*)(Bhg + ((size_t)((d*2+ft)*64 + l))*8);
        bbl.v = *(const bf16x8*)(Blg + ((size_t)((d*2+ft)*64 + l))*8);
        f16v c;
        c = __builtin_amdgcn_mfma_f32_32x32x16_bf16(A1.v, bbh.v, cz, 0,0,0);
        c = __builtin_amdgcn_mfma_f32_32x32x16_bf16(A2.v, bbh.v, c, 0,0,0);
        c = __builtin_amdgcn_mfma_f32_32x32x16_bf16(A1.v, bbl.v, c, 0,0,0);
        #pragma unroll
        for (int r=0;r<16;r++){
          float ev = fmaxf(c[r], 0.f);
          nacc[ft][r>>2][r&3] = fmaf(ldA[r>>2][r&3], ev, nacc[ft][r>>2][r&3]);
        }
      }
    }
    // write neighbor tile rows (C layout: row=(r&3)+8*(r>>2)+4*g, col=em)
    #pragma unroll
    for (int ft=0; ft<2; ft++)
      #pragma unroll
      for (int r=0;r<16;r++){
        int row = (r&3) + ((r>>2)<<3) + (g<<2);
        sNb[((w<<5)+row)*65 + (ft<<5) + em] = nacc[ft][r>>2][r&3];
      }
  }
  __syncthreads();

  // overlay attW onto sA region
  float* sW = sA;
  for (int i=tid; i<4096; i+=256) sW[i] = attWt[i];
  if (tid < 64) sBias[tid] = attBf[tid];
  __syncthreads();

  // per-atom: score -> softmax -> y -> context matvec -> ELU (wave per atom)
  float wa = alW[l], wn = alW[64+l], ab = alB[0];
  for (int a = aLo + w; a < aHi; a += 4){
    int d0 = rowstart[a], d1 = rowstart[a+1];
    int deg = d1 - d0;
    int le0 = d0 - E0;
    float cf = 0.f;
    if (deg > 0){
      float p = wa * atom[(size_t)a*64 + l];
      p += __shfl_xor(p,1);  p += __shfl_xor(p,2);
      p += __shfl_xor(p,4);  p += __shfl_xor(p,8);
      p += __shfl_xor(p,16); p += __shfl_xor(p,32);
      float mx = -1e30f;
      for (int i2=0;i2<deg;i2++){
        float q2 = wn * sNb[(le0+i2)*65 + l];
        q2 += __shfl_xor(q2,1);  q2 += __shfl_xor(q2,2);
        q2 += __shfl_xor(q2,4);  q2 += __shfl_xor(q2,8);
        q2 += __shfl_xor(q2,16); q2 += __shfl_xor(q2,32);
        float s = p + q2 + ab;
        s = (s > 0.f) ? s : 0.01f*s;
        if (l == 0) sScore[le0+i2] = s;
        mx = fmaxf(mx, s);
      }
      float dn = 0.f, y = 0.f;
      for (int i2=0;i2<deg;i2++){
        float ex = __expf(sScore[le0+i2] - mx);
        dn += ex;
        y = fmaf(ex, sNb[(le0+i2)*65 + l], y);
      }
      float ctx = dn * sBias[l];
      #pragma unroll 8
      for (int k=0;k<64;k++){
        ctx = fmaf(__shfl(y,k), sW[k*64 + l], ctx);
      }
      cf = ctx / (dn + 1e-8f);
      cf = (cf > 0.f) ? cf : expm1f(cf);
    }
    cfout[(size_t)a*64 + l] = cf;
  }
}

// ---------------- per-atom: GRU ----------------
__global__ __launch_bounds__(256) void k_gru(
  const float* __restrict__ atom, const float* __restrict__ cfin,
  const float* __restrict__ wqG,
  const float* __restrict__ bih, const float* __restrict__ bhh,
  float* __restrict__ out)
{
  __shared__ float swq[24576];
  __shared__ float sc[4][8][64];
  __shared__ float shh[4][8][64];
  int tid = threadIdx.x;
  int f = tid & 63;
  int w = tid >> 6;
  for (int i=tid; i<6144; i+=256) ((f4*)swq)[i] = ((const f4*)wqG)[i];
  int base = blockIdx.x*32 + w*8;
  #pragma unroll
  for (int a=0; a<8; a++){
    int ga = base + a;
    float cf=0.f, hf=0.f;
    if (ga < NA){
      cf = cfin[(size_t)ga*64 + f];
      hf = atom[(size_t)ga*64 + f];
    }
    sc[w][a][f] = cf; shh[w][a][f] = hf;
  }
  __syncthreads();

  float acc[6][8];
  #pragma unroll
  for (int gg=0;gg<6;gg++)
    #pragma unroll
    for (int a=0;a<8;a++) acc[gg][a] = 0.f;

  for (int kg=0; kg<16; kg++){
    f4 wv[6];
    #pragma unroll
    for (int gg=0;gg<6;gg++) wv[gg] = *(const f4*)&swq[((gg*16+kg)*64 + f)*4];
    #pragma unroll
    for (int a=0;a<8;a++){
      f4 cv = *(const f4*)&sc[w][a][kg*4];
      f4 hv = *(const f4*)&shh[w][a][kg*4];
      #pragma unroll
      for (int j=0;j<4;j++){
        acc[0][a] = fmaf(cv[j], wv[0][j], acc[0][a]);
        acc[1][a] = fmaf(cv[j], wv[1][j], acc[1][a]);
        acc[2][a] = fmaf(cv[j], wv[2][j], acc[2][a]);
        acc[3][a] = fmaf(hv[j], wv[3][j], acc[3][a]);
        acc[4][a] = fmaf(hv[j], wv[4][j], acc[4][a]);
        acc[5][a] = fmaf(hv[j], wv[5][j], acc[5][a]);
      }
    }
  }

  float b0 = bih[f], b1 = bih[64+f], b2 = bih[128+f];
  float h0 = bhh[f], h1 = bhh[64+f], h2 = bhh[128+f];
  #pragma unroll
  for (int a=0;a<8;a++){
    int ga = base + a;
    if (ga < NA){
      float r = 1.f/(1.f + expf(-(acc[0][a] + b0 + acc[3][a] + h0)));
      float z = 1.f/(1.f + expf(-(acc[1][a] + b1 + acc[4][a] + h1)));
      float n = tanhf(acc[2][a] + b2 + r*(acc[5][a] + h2));
      out[(size_t)ga*64 + f] = (1.f - z)*n + z*shh[w][a][f];
    }
  }
}

extern "C" void kernel_launch(void* const* d_in, const int* in_sizes, int n_in,
                              void* d_out, int out_size, void* d_ws, size_t ws_size,
                              hipStream_t stream) {
  const float* atom = (const float*)d_in[0];
  const int*   bidx = (const int*)  d_in[1];
  const float* bond = (const float*)d_in[2];
  const float* encW = (const float*)d_in[3];
  const float* encB = (const float*)d_in[4];
  const float* eg   = (const float*)d_in[5];
  const float* ebt  = (const float*)d_in[6];
  const float* em   = (const float*)d_in[7];
  const float* ev   = (const float*)d_in[8];
  const float* alW  = (const float*)d_in[9];
  const float* alB  = (const float*)d_in[10];
  const float* atW  = (const float*)d_in[11];
  const float* atB  = (const float*)d_in[12];
  const float* agm  = (const float*)d_in[13];
  const float* abt  = (const float*)d_in[14];
  const float* amn  = (const float*)d_in[15];
  const float* avr  = (const float*)d_in[16];
  const float* wih  = (const float*)d_in[17];
  const float* whh  = (const float*)d_in[18];
  const float* bih  = (const float*)d_in[19];
  const float* bhh  = (const float*)d_in[20];

  float* ws = (float*)d_ws;
  unsigned short* Bh = (unsigned short*)(ws + 0);       // 65536 ush = 32768 f
  unsigned short* Bl = (unsigned short*)(ws + 32768);
  float* attWt   = ws + 65536;    // 4096
  float* attBf   = ws + 69632;    // 64
  float* wq      = ws + 69696;    // 24576
  int*   cnt     = (int*)(ws + 94272);    // 10000
  int*   rowstart= (int*)(ws + 104272);   // 10016 (10001 used)
  int*   wofs    = (int*)(ws + 114288);   // 10000
  int*   elist   = (int*)(ws + 124288);   // 40000
  float* cfout   = ws + 164288;   // 640000

  hipMemsetAsync(cnt, 0, NA*sizeof(int), stream);
  k_pre<<<512, 256, 0, stream>>>(encW,encB,eg,ebt,em,ev,
                                 atW,atB,agm,abt,amn,avr,
                                 wih,whh, bidx,
                                 Bh,Bl,attWt,attBf,wq,cnt);
  k_scan<<<1, 256, 0, stream>>>(cnt, rowstart, wofs);
  k_scatter<<<(NE+255)/256, 256, 0, stream>>>(bidx, wofs, elist);
  k_edge<<<625, 256, 0, stream>>>(atom,bidx,bond,Bh,Bl,alW,alB,attWt,attBf,
                                  rowstart,elist,cfout);
  k_gru<<<313, 256, 0, stream>>>(atom,cfout,wq,bih,bhh,(float*)d_out);
}